// Round 11
// baseline (307.473 us; speedup 1.0000x reference)
//
#include <hip/hip_runtime.h>
#include <hip/hip_bf16.h>

#define IN_C  256
#define OUT_C 256
#define HH 56
#define WW 56
#define NN 32
#define XT_H 58
#define XT_W 64
#define WT_BYTES (8*9*256*32*2)  /* 1,179,648 B */

/* xt layout: [chunk8][n32][hp58][wp64][ic32] bf16 */
#define CHST_ELEMS ((size_t)NN * XT_H * XT_W * 32)   /* 3,801,088 elems */
#define CHST_BYTES (CHST_ELEMS * 2)                  /* 7,602,176 B     */

using short8 = __attribute__((ext_vector_type(8))) short;
using f32x4  = __attribute__((ext_vector_type(4))) float;

// ---------------------------------------------------------------------------
// Fused prepass: x NCHW fp32 -> xt bf16 [chunk][n][hp][wp][ic32] (halo zeroed),
// w OIHW fp32 -> wt bf16 [chunk][tap][oc256][ic32].
// ---------------------------------------------------------------------------
__global__ void k_prep(const float* __restrict__ x, const float* __restrict__ w,
                       __hip_bfloat16* __restrict__ wt, __hip_bfloat16* __restrict__ xt) {
  const int b = blockIdx.x, tid = threadIdx.x;

  if (b >= NN * XT_H) {
    // weight part: 576 blocks x 1024 elems (576*1024 == 256*256*9)
    const int base = (b - NN * XT_H) * 1024;
#pragma unroll
    for (int k = 0; k < 4; ++k) {
      int idx = base + k * 256 + tid;
      int kw = idx % 3; int t1 = idx / 3;
      int kh = t1 % 3;  int t2 = t1 / 3;
      int ic = t2 % IN_C; int oc = t2 / IN_C;
      int tap = kh * 3 + kw;
      wt[((((ic >> 5) * 9 + tap) * 256 + oc) * 32) + (ic & 31)] = __float2bfloat16(w[idx]);
    }
    return;
  }

  const int n = b / XT_H, hp = b % XT_H;
  const size_t rowbase = (size_t)(n * XT_H + hp) * (XT_W * 32);  // elems within a chunk plane

  if (hp == 0 || hp == XT_H - 1) {
    // top/bottom halo row: zero 64 cols x 32 ic in all 8 chunk planes
    int4 z; z.x = z.y = z.z = z.w = 0;
#pragma unroll
    for (int c = 0; c < 8; ++c)
      ((int4*)(xt + c * CHST_ELEMS + rowbase))[tid] = z;
    return;
  }

  const int h = hp - 1;
  __shared__ __hip_bfloat16 tile[56][264];   // [w][ic], padded stride

  {
    const int ic = tid;
    const float* src = x + (((size_t)n * IN_C + ic) * HH + h) * WW;
#pragma unroll
    for (int j = 0; j < 14; ++j) {
      float4 v = ((const float4*)src)[j];
      tile[4 * j + 0][ic] = __float2bfloat16(v.x);
      tile[4 * j + 1][ic] = __float2bfloat16(v.y);
      tile[4 * j + 2][ic] = __float2bfloat16(v.z);
      tile[4 * j + 3][ic] = __float2bfloat16(v.w);
    }
  }
  {
    // w-halo: wp = 0 and 57..63, all chunks: 8 chunks x 8 cells x 4 slots
    int4 z; z.x = z.y = z.z = z.w = 0;
    int c = tid >> 5, c5 = tid & 31;
    int cell = c5 >> 2, slot = c5 & 3;
    int wp = (cell == 0) ? 0 : (56 + cell);
    *(int4*)(xt + c * CHST_ELEMS + rowbase + wp * 32 + slot * 8) = z;
  }
  __syncthreads();
  // interior store: 56 wq x 32 segs (seg = chunk*4 + slot), 16B per lane
#pragma unroll
  for (int k = 0; k < 7; ++k) {
    int e = k * 256 + tid;
    int wq = e >> 5, seg = e & 31;
    short8 v = *(const short8*)&tile[wq][seg * 8];
    *(short8*)(xt + (seg >> 2) * CHST_ELEMS + rowbase + (size_t)(wq + 1) * 32 + (seg & 3) * 8) = v;
  }
}

// ---------------------------------------------------------------------------
// main conv: LDS-FREE. 1 wave per block (64 thr), wave = 112 px x 64 oc.
// Grid 3584 (= 8 blocks/CU, fine-grained). x fragments read directly from
// global (1KB coalesced per read, L1/L2-served); weights global->VGPR 4-slot
// rolling pipeline. xf double-buffered: phase p+1 loads overlap phase p MFMAs.
// No barriers, no vmcnt bookkeeping (compiler-counted waits on reg loads).
// ---------------------------------------------------------------------------
__global__ __launch_bounds__(64, 2) void k_conv(
    const __hip_bfloat16* __restrict__ wt, const __hip_bfloat16* __restrict__ xt,
    const float* __restrict__ bias, float* __restrict__ out) {
  const int lane = threadIdx.x;
  const int cc   = lane & 15, g = lane >> 4;

  // XCD-bijective swizzle (3584 % 8 == 0); consecutive wk share px-group/n
  const int wk  = (blockIdx.x & 7) * 448 + (blockIdx.x >> 3);
  const int n   = wk / 112;
  const int r   = wk - n * 112;
  const int pxg = r >> 2, oc4 = r & 3;
  const int h0  = pxg * 2;                 // band covers output rows h0, h0+1

  int xoff[7];                              // byte offset of fragment (pt) at tap (0,0)
#pragma unroll
  for (int pt = 0; pt < 7; ++pt) {
    int p = pt * 16 + cc;
    int rp = (p >= 56) ? 1 : 0, wp = p - 56 * rp;
    xoff[pt] = ((rp * 64 + wp) * 32 + g * 8) * 2;
  }
  const char* xtn = (const char*)xt + (size_t)(n * XT_H + h0) * (XT_W * 32) * 2;

  const int ocb = oc4 * 64;
  const __hip_bfloat16* wlane = wt + (size_t)(ocb + cc) * 32 + g * 8;

  f32x4 acc[4][7];
#pragma unroll
  for (int a = 0; a < 4; ++a)
#pragma unroll
    for (int bb = 0; bb < 7; ++bb) acc[a][bb] = (f32x4){0.f, 0.f, 0.f, 0.f};

  auto loadw1 = [&](int ph, int oct) -> short8 {
    return *(const short8*)(wlane + (size_t)ph * 8192 + oct * 512);
  };

  short8 wA, wB, wC, wD;
  short8 xfA[7], xfB[7];

#define LDXG(i_, kh_, kw_, CHB_) \
    (*(const short8*)(xtn + (CHB_) + xoff[i_] + (kh_) * 4096 + (kw_) * 64))

  // prologue: tap0 fragments of chunk 0 + first 3 weight octs
#pragma unroll
  for (int pt = 0; pt < 7; ++pt) xfA[pt] = LDXG(pt, 0, 0, (size_t)0);
  wA = loadw1(0, 0);
  wB = loadw1(0, 1);
  wC = loadw1(0, 2);

#define MFMA7(X_, W_, oct_) do {                                                      \
    __builtin_amdgcn_s_setprio(1);                                                    \
    _Pragma("unroll")                                                                 \
    for (int pt = 0; pt < 7; ++pt)                                                    \
      acc[oct_][pt] = __builtin_amdgcn_mfma_f32_16x16x32_bf16(W_, X_[pt], acc[oct_][pt], 0, 0, 0); \
    __builtin_amdgcn_s_setprio(0);                                                    \
  } while (0)

  // consume XU_ at phase ph_; prefetch next phase's frags (nkh_,nkw_, chunk
  // base NCHB_) into XL_; slide the 4-slot weight pipeline.
#define PHASE(ph_, XU_, XL_, nkh_, nkw_, NCHB_) do {                                  \
    wD = loadw1(ph_, 3);                                                              \
    XL_[0] = LDXG(0, nkh_, nkw_, NCHB_); XL_[1] = LDXG(1, nkh_, nkw_, NCHB_);         \
    MFMA7(XU_, wA, 0);                                                                \
    wA = loadw1((ph_) + 1, 0);                                                        \
    XL_[2] = LDXG(2, nkh_, nkw_, NCHB_); XL_[3] = LDXG(3, nkh_, nkw_, NCHB_);         \
    MFMA7(XU_, wB, 1);                                                                \
    wB = loadw1((ph_) + 1, 1);                                                        \
    XL_[4] = LDXG(4, nkh_, nkw_, NCHB_); XL_[5] = LDXG(5, nkh_, nkw_, NCHB_);         \
    MFMA7(XU_, wC, 2);                                                                \
    wC = loadw1((ph_) + 1, 2);                                                        \
    XL_[6] = LDXG(6, nkh_, nkw_, NCHB_);                                              \
    MFMA7(XU_, wD, 3);                                                                \
  } while (0)

#define PHASE_END(ph_, XU_) do {                                                      \
    wD = loadw1(ph_, 3);                                                              \
    MFMA7(XU_, wA, 0);                                                                \
    MFMA7(XU_, wB, 1);                                                                \
    MFMA7(XU_, wC, 2);                                                                \
    MFMA7(XU_, wD, 3);                                                                \
  } while (0)

  // 2 chunks per iteration (9 phases are odd -> parity alternates per chunk)
  size_t chb = 0;
  for (int ch2 = 0; ch2 < 4; ++ch2) {
    const int phA = (2 * ch2) * 9;
    // chunk even: tap0 in xfA
    PHASE(phA + 0, xfA, xfB, 0, 1, chb);
    PHASE(phA + 1, xfB, xfA, 0, 2, chb);
    PHASE(phA + 2, xfA, xfB, 1, 0, chb);
    PHASE(phA + 3, xfB, xfA, 1, 1, chb);
    PHASE(phA + 4, xfA, xfB, 1, 2, chb);
    PHASE(phA + 5, xfB, xfA, 2, 0, chb);
    PHASE(phA + 6, xfA, xfB, 2, 1, chb);
    PHASE(phA + 7, xfB, xfA, 2, 2, chb);
    PHASE(phA + 8, xfA, xfB, 0, 0, chb + CHST_BYTES);   // prefetch next chunk tap0
    chb += CHST_BYTES;
    const int phB = (2 * ch2 + 1) * 9;
    // chunk odd: tap0 in xfB
    PHASE(phB + 0, xfB, xfA, 0, 1, chb);
    PHASE(phB + 1, xfA, xfB, 0, 2, chb);
    PHASE(phB + 2, xfB, xfA, 1, 0, chb);
    PHASE(phB + 3, xfA, xfB, 1, 1, chb);
    PHASE(phB + 4, xfB, xfA, 1, 2, chb);
    PHASE(phB + 5, xfA, xfB, 2, 0, chb);
    PHASE(phB + 6, xfB, xfA, 2, 1, chb);
    PHASE(phB + 7, xfA, xfB, 2, 2, chb);
    if (ch2 < 3) {
      PHASE(phB + 8, xfB, xfA, 0, 0, chb + CHST_BYTES);
      chb += CHST_BYTES;
    } else {
      PHASE_END(phB + 8, xfB);
    }
  }
#undef PHASE
#undef PHASE_END
#undef LDXG
#undef MFMA7

  // epilogue: D row(4g+rr)=oc, D col(cc)=pixel -> coalesced stores over cc
  int rp_[7], wp_[7];
#pragma unroll
  for (int pt = 0; pt < 7; ++pt) {
    int p = pt * 16 + cc;
    rp_[pt] = (p >= 56) ? 1 : 0; wp_[pt] = p - 56 * rp_[pt];
  }
#pragma unroll
  for (int oct = 0; oct < 4; ++oct) {
    const int oc0 = ocb + oct * 16 + 4 * g;
#pragma unroll
    for (int rr = 0; rr < 4; ++rr) {
      const float bv = bias[oc0 + rr];
      const size_t obase = ((size_t)n * OUT_C + (oc0 + rr)) * (HH * WW);
#pragma unroll
      for (int pt = 0; pt < 7; ++pt)
        out[obase + (size_t)(h0 + rp_[pt]) * 56 + wp_[pt]] = acc[oct][pt][rr] + bv;
    }
  }
}

extern "C" void kernel_launch(void* const* d_in, const int* in_sizes, int n_in,
                              void* d_out, int out_size, void* d_ws, size_t ws_size,
                              hipStream_t stream) {
  const float* x    = (const float*)d_in[0];
  const float* w    = (const float*)d_in[1];
  const float* bias = (const float*)d_in[2];
  float* out        = (float*)d_out;

  __hip_bfloat16* wt = (__hip_bfloat16*)d_ws;
  __hip_bfloat16* xt = (__hip_bfloat16*)((char*)d_ws + WT_BYTES);

  k_prep<<<NN * XT_H + 576, 256, 0, stream>>>(x, w, wt, xt);
  k_conv<<<NN * 112, 64, 0, stream>>>(wt, xt, bias, out);
}

// Round 12
// 145.004 us; speedup vs baseline: 2.1205x; 2.1205x over previous
//
#include <hip/hip_runtime.h>
#include <hip/hip_bf16.h>

#define IN_C  256
#define OUT_C 256
#define HH 56
#define WW 56
#define NN 32
#define XT_H 58
#define XT_W 64
#define WT_BYTES (8*9*256*32*2)  /* 1,179,648 B */

#define XS_BYTES 24576                /* 6 rows x 64 cols x 64B */
#define LDS_TOTAL (2*XS_BYTES)        /* 48 KiB */

using short8 = __attribute__((ext_vector_type(8))) short;
using f32x4  = __attribute__((ext_vector_type(4))) float;

__device__ __forceinline__ void gload_lds16(const void* g, void* l) {
  __builtin_amdgcn_global_load_lds((const __attribute__((address_space(1))) void*)g,
                                   (__attribute__((address_space(3))) void*)l,
                                   16, 0, 0);
}

#define VMWAIT(N) asm volatile("s_waitcnt vmcnt(" #N ")" ::: "memory")

// ---------------------------------------------------------------------------
// Fused prepass (R6/R7 version): x NCHW fp32 -> xt bf16 [n][hp][wp][ic256]
// (halo zeroed), w OIHW fp32 -> wt bf16 [chunk][tap][oc256][ic32].
// ---------------------------------------------------------------------------
__global__ void k_prep(const float* __restrict__ x, const float* __restrict__ w,
                       __hip_bfloat16* __restrict__ wt, __hip_bfloat16* __restrict__ xt) {
  const int b = blockIdx.x, tid = threadIdx.x;

  if (b >= NN * XT_H) {
    const int base = (b - NN * XT_H) * 1024;
#pragma unroll
    for (int k = 0; k < 4; ++k) {
      int idx = base + k * 256 + tid;
      int kw = idx % 3; int t1 = idx / 3;
      int kh = t1 % 3;  int t2 = t1 / 3;
      int ic = t2 % IN_C; int oc = t2 / IN_C;
      int tap = kh * 3 + kw;
      wt[((((ic >> 5) * 9 + tap) * 256 + oc) * 32) + (ic & 31)] = __float2bfloat16(w[idx]);
    }
    return;
  }

  const int n = b / XT_H, hp = b % XT_H;
  __hip_bfloat16* row = xt + (size_t)(n * XT_H + hp) * XT_W * 256;

  if (hp == 0 || hp == XT_H - 1) {
    int4 z; z.x = z.y = z.z = z.w = 0;
#pragma unroll
    for (int k = 0; k < 8; ++k) ((int4*)row)[k * 256 + tid] = z;
    return;
  }

  const int h = hp - 1;
  __shared__ __hip_bfloat16 tile[56][264];

  {
    const int ic = tid;
    const float* src = x + (((size_t)n * IN_C + ic) * HH + h) * WW;
#pragma unroll
    for (int j = 0; j < 14; ++j) {
      float4 v = ((const float4*)src)[j];
      tile[4 * j + 0][ic] = __float2bfloat16(v.x);
      tile[4 * j + 1][ic] = __float2bfloat16(v.y);
      tile[4 * j + 2][ic] = __float2bfloat16(v.z);
      tile[4 * j + 3][ic] = __float2bfloat16(v.w);
    }
  }
  {
    int4 z; z.x = z.y = z.z = z.w = 0;
    int cell = tid >> 5, s = tid & 31;
    int wp = (cell == 0) ? 0 : (56 + cell);
    ((int4*)(row + (size_t)wp * 256))[s] = z;
  }
  __syncthreads();
#pragma unroll
  for (int k = 0; k < 7; ++k) {
    int e = k * 256 + tid;
    int wq = e >> 5, seg = e & 31;
    short8 v = *(const short8*)&tile[wq][seg * 8];
    *(short8*)(row + (size_t)(wq + 1) * 256 + seg * 8) = v;
  }
}

// ---------------------------------------------------------------------------
// main conv: R7 skeleton + R10's PROVEN zero-conflict LDS swizzle, spill-safe.
// block = 4 waves, 224 px x 128 oc; wave = 112 px x 64 oc; 2 blocks/CU.
// LDS cell (col, slot): slot = (g + (col>>1)) & 3  -> SQ_LDS_BANK_CONFLICT = 0
// (R10-measured). All 21 swizzled offsets PRECOMPUTED (xoffk[3][7]) -- no
// per-read temps. xf SINGLE-buffered (-28 regs) so total ~218 < 256: no spill.
// Weights global(L2)->VGPR 4-slot rolling pipeline; 8 barriers total.
// ---------------------------------------------------------------------------
__global__ __launch_bounds__(256, 2) void k_conv(
    const __hip_bfloat16* __restrict__ wt, const __hip_bfloat16* __restrict__ xt,
    const float* __restrict__ bias, float* __restrict__ out) {
  extern __shared__ __align__(16) char lds[];
  char* xs_c = lds;                    // [2][row6][col64][slot4][16B]

  const int tid  = threadIdx.x;
  const int wid  = tid >> 6, lane = tid & 63;
  const int cc   = lane & 15, g = lane >> 4;
  const int wn   = wid & 1,  wm = wid >> 1;

  // XCD-bijective swizzle (896 % 8 == 0)
  const int work = (blockIdx.x & 7) * 112 + (blockIdx.x >> 3);
  const int n  = work / 28;
  const int rem = work - n * 28;
  const int q  = rem >> 1, oh = rem & 1;
  const int h0 = q * 4;

  // precomputed swizzled offsets: xoffk[kw][pt] (R10 slot math, zero conflicts)
  int xoffk[3][7];
#pragma unroll
  for (int kw = 0; kw < 3; ++kw)
#pragma unroll
    for (int pt = 0; pt < 7; ++pt) {
      int p = wm * 112 + pt * 16 + cc;
      int rp = p / 56, wp = p - rp * 56;
      int col = wp + kw;
      xoffk[kw][pt] = rp * 4096 + col * 64 + (((g + (col >> 1)) & 3) * 16);
    }
  const int ocb = oh * 128 + wn * 64;
  const __hip_bfloat16* wlane = wt + (size_t)(ocb + cc) * 32 + g * 8;

  f32x4 acc[4][7];
#pragma unroll
  for (int a = 0; a < 4; ++a)
#pragma unroll
    for (int bb = 0; bb < 7; ++bb) acc[a][bb] = (f32x4){0.f, 0.f, 0.f, 0.f};

  const __hip_bfloat16* xtn = xt + (size_t)(n * XT_H + h0) * XT_W * 256;

  // inverse-swizzled DMA source (R10-verified): phys slot l&3 at col
  // colq*16+(l>>2) receives ic-group glog = ((l&3) - (l>>3)) & 3
  const int glog = ((lane & 3) - (lane >> 3)) & 3;
  auto stage_x = [&](int buf, int ch) {
#pragma unroll
    for (int i = 0; i < 6; ++i) {
      int s = wid * 6 + i;
      int rowc = s >> 2, colq = s & 3;
      const __hip_bfloat16* src = xtn + (size_t)(rowc * 64 + colq * 16 + (lane >> 2)) * 256
                                      + ch * 32 + glog * 8;
      gload_lds16(src, xs_c + buf * XS_BYTES + rowc * 4096 + colq * 1024);
    }
  };
  auto loadw1 = [&](int ph, int oct) -> short8 {
    return *(const short8*)(wlane + (size_t)ph * 8192 + oct * 512);
  };

  short8 wA, wB, wC, wD;

  stage_x(0, 0);
  __builtin_amdgcn_sched_barrier(0);
  wA = loadw1(0, 0);
  wB = loadw1(0, 1);
  wC = loadw1(0, 2);

#define MFMA7(X_, W_, oct_) do {                                                      \
    __builtin_amdgcn_s_setprio(1);                                                    \
    _Pragma("unroll")                                                                 \
    for (int pt = 0; pt < 7; ++pt)                                                    \
      acc[oct_][pt] = __builtin_amdgcn_mfma_f32_16x16x32_bf16(W_, X_[pt], acc[oct_][pt], 0, 0, 0); \
    __builtin_amdgcn_s_setprio(0);                                                    \
  } while (0)

  // single-buffered xf: read 7 frags (conflict-free), then 4 MFMA groups with
  // the rolling weight pipeline sliding one phase.
#define PHASE(ph_, kh_, kw_) do {                                                     \
    short8 xf[7];                                                                     \
    _Pragma("unroll")                                                                 \
    for (int pt = 0; pt < 7; ++pt)                                                    \
      xf[pt] = *(const short8*)(xb + xoffk[kw_][pt] + (kh_) * 4096);                  \
    wD = loadw1(ph_, 3);                                                              \
    MFMA7(xf, wA, 0);                                                                 \
    wA = loadw1((ph_) + 1, 0);                                                        \
    MFMA7(xf, wB, 1);                                                                 \
    wB = loadw1((ph_) + 1, 1);                                                        \
    MFMA7(xf, wC, 2);                                                                 \
    wC = loadw1((ph_) + 1, 2);                                                        \
    MFMA7(xf, wD, 3);                                                                 \
  } while (0)

  for (int ch = 0; ch < 8; ++ch) {
    // newest 3 in flight = rolling w loads; x DMA (older in FIFO) drained
    VMWAIT(3);
    __builtin_amdgcn_s_barrier();
    if (ch < 7) {
      stage_x((ch + 1) & 1, ch + 1);
      __builtin_amdgcn_sched_barrier(0);
    }
    const char* xb = xs_c + ((ch & 1) ? XS_BYTES : 0);
    const int ph0 = ch * 9;
    PHASE(ph0 + 0, 0, 0);
    PHASE(ph0 + 1, 0, 1);
    PHASE(ph0 + 2, 0, 2);
    PHASE(ph0 + 3, 1, 0);
    PHASE(ph0 + 4, 1, 1);
    PHASE(ph0 + 5, 1, 2);
    PHASE(ph0 + 6, 2, 0);
    PHASE(ph0 + 7, 2, 1);
    PHASE(ph0 + 8, 2, 2);
  }
#undef PHASE
#undef MFMA7

  // epilogue: D row(4g+r)=oc, D col(cc)=pixel -> coalesced stores over cc
  int rp_[7], wp_[7];
#pragma unroll
  for (int pt = 0; pt < 7; ++pt) {
    int p = wm * 112 + pt * 16 + cc;
    rp_[pt] = p / 56; wp_[pt] = p - rp_[pt] * 56;
  }
#pragma unroll
  for (int oct = 0; oct < 4; ++oct) {
    const int oc0 = ocb + oct * 16 + 4 * g;
#pragma unroll
    for (int r = 0; r < 4; ++r) {
      const float bv = bias[oc0 + r];
      const size_t obase = ((size_t)n * OUT_C + (oc0 + r)) * (HH * WW);
#pragma unroll
      for (int pt = 0; pt < 7; ++pt)
        out[obase + (size_t)(h0 + rp_[pt]) * 56 + wp_[pt]] = acc[oct][pt][r] + bv;
    }
  }
}

extern "C" void kernel_launch(void* const* d_in, const int* in_sizes, int n_in,
                              void* d_out, int out_size, void* d_ws, size_t ws_size,
                              hipStream_t stream) {
  const float* x    = (const float*)d_in[0];
  const float* w    = (const float*)d_in[1];
  const float* bias = (const float*)d_in[2];
  float* out        = (float*)d_out;

  __hip_bfloat16* wt = (__hip_bfloat16*)d_ws;
  __hip_bfloat16* xt = (__hip_bfloat16*)((char*)d_ws + WT_BYTES);

  hipFuncSetAttribute((const void*)k_conv,
                      hipFuncAttributeMaxDynamicSharedMemorySize, LDS_TOTAL);

  k_prep<<<NN * XT_H + 576, 256, 0, stream>>>(x, w, wt, xt);
  k_conv<<<NN * 14 * 2, 256, LDS_TOTAL, stream>>>(wt, xt, bias, out);
}